// Round 16
// baseline (12480.676 us; speedup 1.0000x reference)
//
#include <hip/hip_runtime.h>
#include <math.h>

#define B 512
#define S 256
#define D 64
#define H 512
#define BH (B*H)

// shared ws layout (floats): h 2 slots @0 | c 2 slots @2BH (persist uses slot0 only)
// | xatt @4BH | flags (uints) @4BH+B*D
#define HBUF_OFF 0
#define CBUF_OFF (2*BH)
#define XATT_OFF (4*BH)
#define FLAGS_OFF (4*BH + B*D)

#define WAIT_VM(n) asm volatile("s_waitcnt vmcnt(" #n ")" ::: "memory")

__device__ __forceinline__ void ldg_sc_nw(float4& r, const float* p) {
    asm volatile("global_load_dwordx4 %0, %1, off sc0 sc1" : "=v"(r) : "v"(p));
}
__device__ __forceinline__ void st_sc_f1(float* p, float v) {
    asm volatile("global_store_dword %0, %1, off sc0 sc1" :: "v"(p), "v"(v));
}
__device__ __forceinline__ void waitf(unsigned int* f, unsigned int tgt) {
    if (threadIdx.x == 0) {
        unsigned int spin = 0;
        while (__hip_atomic_load(f, __ATOMIC_RELAXED, __HIP_MEMORY_SCOPE_AGENT) < tgt) {
            __builtin_amdgcn_s_sleep(2);
            if (++spin > (1u << 18)) break;   // finite bail: no hang
        }
    }
    __syncthreads();
}
__device__ __forceinline__ void bumpf(unsigned int* f) {
    __hip_atomic_fetch_add(f, 1u, __ATOMIC_RELAXED, __HIP_MEMORY_SCOPE_AGENT);
}

// =================== persistent kernel (3-launch path) ===================
// 256 blocks, 1/CU. bid: u = bid&15 (unit tile), r = bid>>4 (row tile).
// Group = 16 blocks sharing row tile r. attn rows of block: r*32+u*2, +1.
__global__ __launch_bounds__(256, 1) void persist_kernel(
    const float* __restrict__ x, const float* __restrict__ Wa,
    const float* __restrict__ Ua, const float* __restrict__ ba,
    const float* __restrict__ Va,
    const float* __restrict__ Wih, const float* __restrict__ Whh,
    const float* __restrict__ bih, const float* __restrict__ bhh,
    float* __restrict__ ws, unsigned int* __restrict__ flags)
{
    const int tid = threadIdx.x;
    const int u = blockIdx.x & 15;
    const int r = blockIdx.x >> 4;
    const int u0 = u * 32, r0 = r * 32;
    const int ar0 = r0 + u * 2;          // own attn rows: ar0, ar0+1

    __shared__ float h_l[32][516];       // 66.0 KB  (pitch 516: conflict-free)
    __shared__ float w_lds[4][32][68];   // 34.8 KB
    __shared__ float c2[2][512];         //  4.0 KB
    __shared__ float xatt_l[32][68];     //  8.7 KB
    __shared__ float c_t[32][36];        //  4.6 KB
    __shared__ float part[2][2][64];
    __shared__ float ta[2][64];
    __shared__ float pv[2][2][64];

    float* h32 = ws + HBUF_OFF;
    float* c32 = ws + CBUF_OFF;          // single slot (flag ordering makes safe)
    float* xatt = ws + XATT_OFF;
    unsigned int* hflag = flags + r * 16;
    unsigned int* xflag = flags + 256 + r * 16;

    const int tm = tid & 7, tn = tid >> 3;

    // ---- init own (u,r) tile of h slot0 and c to zero ----
    #pragma unroll
    for (int i = 0; i < 4; ++i) {
        int e = tid + i * 256;           // 0..1023
        int row = e >> 5, col = e & 31;
        st_sc_f1(h32 + (size_t)(r0 + row) * H + u0 + col, 0.f);
        st_sc_f1(c32 + (size_t)(r0 + row) * H + u0 + col, 0.f);
    }
    WAIT_VM(0);
    __syncthreads();
    if (tid == 0) bumpf(hflag);          // group init → hflag reaches 16

    for (int ts = 0; ts < S; ++ts) {
        const int rd = ts & 1, wrs = rd ^ 1;
        const unsigned int tgt = 16u * (unsigned int)(ts + 1);

        waitf(hflag, tgt);               // h(ts), c(ts) published group-wide

        // ---- stage h(ts)[32 rows][512] + c(ts)[2 own rows] into LDS ----
        {
            const float* hbR = h32 + (size_t)rd * BH + (size_t)r0 * H;  // 64KB contiguous
            float4 a0,a1,a2,a3,a4,a5,a6,a7, b0,b1,b2,b3,b4,b5,b6,b7, cc;
            ldg_sc_nw(a0, hbR + (size_t)(tid +  0*256) * 4);
            ldg_sc_nw(a1, hbR + (size_t)(tid +  1*256) * 4);
            ldg_sc_nw(a2, hbR + (size_t)(tid +  2*256) * 4);
            ldg_sc_nw(a3, hbR + (size_t)(tid +  3*256) * 4);
            ldg_sc_nw(a4, hbR + (size_t)(tid +  4*256) * 4);
            ldg_sc_nw(a5, hbR + (size_t)(tid +  5*256) * 4);
            ldg_sc_nw(a6, hbR + (size_t)(tid +  6*256) * 4);
            ldg_sc_nw(a7, hbR + (size_t)(tid +  7*256) * 4);
            ldg_sc_nw(b0, hbR + (size_t)(tid +  8*256) * 4);
            ldg_sc_nw(b1, hbR + (size_t)(tid +  9*256) * 4);
            ldg_sc_nw(b2, hbR + (size_t)(tid + 10*256) * 4);
            ldg_sc_nw(b3, hbR + (size_t)(tid + 11*256) * 4);
            ldg_sc_nw(b4, hbR + (size_t)(tid + 12*256) * 4);
            ldg_sc_nw(b5, hbR + (size_t)(tid + 13*256) * 4);
            ldg_sc_nw(b6, hbR + (size_t)(tid + 14*256) * 4);
            ldg_sc_nw(b7, hbR + (size_t)(tid + 15*256) * 4);
            ldg_sc_nw(cc, c32 + (size_t)(ar0 + (tid >> 7)) * H + (tid & 127) * 4);
            WAIT_VM(9);                  // first 8 arrived (9 still in flight)
            __builtin_amdgcn_sched_barrier(0);
            #define WRH(v, j) *(float4*)&h_l[(tid + (j)*256) >> 7][((tid + (j)*256) & 127) * 4] = v
            WRH(a0,0); WRH(a1,1); WRH(a2,2); WRH(a3,3);
            WRH(a4,4); WRH(a5,5); WRH(a6,6); WRH(a7,7);
            WAIT_VM(0);
            __builtin_amdgcn_sched_barrier(0);
            WRH(b0,8); WRH(b1,9); WRH(b2,10); WRH(b3,11);
            WRH(b4,12); WRH(b5,13); WRH(b6,14); WRH(b7,15);
            #undef WRH
            *(float4*)&c2[tid >> 7][(tid & 127) * 4] = cc;
        }
        __syncthreads();

        // ---- attention for own 2 rows (R2 body; h/c from LDS) ----
        {
            const int d = tid & 63;
            const int rr = (tid >> 6) & 1;
            const int p = tid >> 7;
            const int brow = ar0 + rr;
            const int lr = u * 2 + rr;
            const float* __restrict__ xrow = x + ((size_t)brow * S + ts) * D;

            float a = 0.f;
            if (p == 0) {
                a = ba[d];
                #pragma unroll 8
                for (int k = 0; k < D; ++k) a += xrow[k] * Wa[k*D + d];
                #pragma unroll 8
                for (int k = 0; k < H; ++k) a += h_l[lr][k] * Ua[k*D + d];
            } else {
                #pragma unroll 8
                for (int k = 0; k < H; ++k) a += c2[rr][k] * Ua[(size_t)(H + k)*D + d];
            }
            part[rr][p][d] = a;
            __syncthreads();
            if (p == 0) ta[rr][d] = tanhf(part[rr][0][d] + part[rr][1][d]);
            __syncthreads();
            float av = 0.f;
            {
                const int k0 = p * 32;
                #pragma unroll 8
                for (int k = k0; k < k0 + 32; ++k) av += ta[rr][k] * Va[k*D + d];
            }
            pv[rr][p][d] = av;
            __syncthreads();
            float v = pv[rr][0][d] + pv[rr][1][d];
            float m = v;
            #pragma unroll
            for (int o = 32; o > 0; o >>= 1) m = fmaxf(m, __shfl_xor(m, o));
            float e = expf(v - m);
            float ssum = e;
            #pragma unroll
            for (int o = 32; o > 0; o >>= 1) ssum += __shfl_xor(ssum, o);
            if (p == 0) {
                st_sc_f1(xatt + (size_t)brow * D + d, (e / ssum) * xrow[d]);
            }
            WAIT_VM(0);
        }
        __syncthreads();
        if (tid == 0) bumpf(xflag);

        // ---- gates: chunks 0..7 over (h_l, Whh) — R2 body verbatim ----
        float acc[4][4];
        #pragma unroll
        for (int i = 0; i < 4; ++i)
            #pragma unroll
            for (int q = 0; q < 4; ++q) acc[i][q] = 0.f;

        for (int kb = 0; kb < 8; ++kb) {
            __syncthreads();
            #pragma unroll
            for (int it = 0; it < 8; ++it) {
                int j = tid + it*256;
                int f4c = j & 15, row = j >> 4;
                int uu = row & 31, q = row >> 5;
                float4 v = *(const float4*)(Whh + (size_t)(q*H + u0 + uu)*H + kb*64 + f4c*4);
                *(float4*)&w_lds[q][uu][f4c*4] = v;
            }
            __syncthreads();
            #pragma unroll
            for (int k4 = 0; k4 < 16; ++k4) {
                float4 wv[4], hv[4];
                #pragma unroll
                for (int q = 0; q < 4; ++q)
                    wv[q] = *(const float4*)&w_lds[q][tn][k4*4];
                #pragma unroll
                for (int i = 0; i < 4; ++i)
                    hv[i] = *(const float4*)&h_l[tm + 8*i][kb*64 + k4*4];
                #pragma unroll
                for (int i = 0; i < 4; ++i)
                    #pragma unroll
                    for (int q = 0; q < 4; ++q) {
                        acc[i][q] = fmaf(hv[i].x, wv[q].x, acc[i][q]);
                        acc[i][q] = fmaf(hv[i].y, wv[q].y, acc[i][q]);
                        acc[i][q] = fmaf(hv[i].z, wv[q].z, acc[i][q]);
                        acc[i][q] = fmaf(hv[i].w, wv[q].w, acc[i][q]);
                    }
            }
        }

        // ---- chunk 8: xatt @ Wih (+ fetch c_old tile) ----
        waitf(xflag, tgt);               // also separates chunk-7 reads from restage
        {
            float4 xa0, xa1, ctv;
            ldg_sc_nw(xa0, xatt + (size_t)(r0 + (tid >> 4)) * D + (tid & 15) * 4);
            ldg_sc_nw(xa1, xatt + (size_t)(r0 + ((tid + 256) >> 4)) * D + ((tid + 256) & 15) * 4);
            ldg_sc_nw(ctv, c32 + (size_t)(r0 + (tid >> 3)) * H + u0 + (tid & 7) * 4);
            #pragma unroll
            for (int it = 0; it < 8; ++it) {
                int j = tid + it*256;
                int f4c = j & 15, row = j >> 4;
                int uu = row & 31, q = row >> 5;
                float4 v = *(const float4*)(Wih + (size_t)(q*H + u0 + uu)*D + f4c*4);
                *(float4*)&w_lds[q][uu][f4c*4] = v;
            }
            WAIT_VM(0);
            __builtin_amdgcn_sched_barrier(0);
            *(float4*)&xatt_l[tid >> 4][(tid & 15) * 4] = xa0;
            *(float4*)&xatt_l[(tid + 256) >> 4][((tid + 256) & 15) * 4] = xa1;
            *(float4*)&c_t[tid >> 3][(tid & 7) * 4] = ctv;
        }
        __syncthreads();
        #pragma unroll
        for (int k4 = 0; k4 < 16; ++k4) {
            float4 wv[4], hv[4];
            #pragma unroll
            for (int q = 0; q < 4; ++q)
                wv[q] = *(const float4*)&w_lds[q][tn][k4*4];
            #pragma unroll
            for (int i = 0; i < 4; ++i)
                hv[i] = *(const float4*)&xatt_l[tm + 8*i][k4*4];
            #pragma unroll
            for (int i = 0; i < 4; ++i)
                #pragma unroll
                for (int q = 0; q < 4; ++q) {
                    acc[i][q] = fmaf(hv[i].x, wv[q].x, acc[i][q]);
                    acc[i][q] = fmaf(hv[i].y, wv[q].y, acc[i][q]);
                    acc[i][q] = fmaf(hv[i].z, wv[q].z, acc[i][q]);
                    acc[i][q] = fmaf(hv[i].w, wv[q].w, acc[i][q]);
                }
        }

        // ---- LSTM update + publish h(ts+1), c(ts+1) ----
        {
            const int ug = u0 + tn;
            const float bs0 = bih[0*H + ug] + bhh[0*H + ug];
            const float bs1 = bih[1*H + ug] + bhh[1*H + ug];
            const float bs2 = bih[2*H + ug] + bhh[2*H + ug];
            const float bs3 = bih[3*H + ug] + bhh[3*H + ug];
            float* __restrict__ hW = h32 + (size_t)wrs * BH;
            #pragma unroll
            for (int i = 0; i < 4; ++i) {
                const int b = r0 + tm + 8*i;
                float gi = acc[i][0] + bs0;
                float gf = acc[i][1] + bs1;
                float gg = acc[i][2] + bs2;
                float go = acc[i][3] + bs3;
                float c_old = c_t[tm + 8*i][tn];
                float si = 1.f / (1.f + expf(-gi));
                float sf = 1.f / (1.f + expf(-gf));
                float so = 1.f / (1.f + expf(-go));
                float cn = sf * c_old + si * tanhf(gg);
                float hn = so * tanhf(cn);
                st_sc_f1(c32 + (size_t)b * H + ug, cn);
                st_sc_f1(hW + (size_t)b * H + ug, hn);
            }
            WAIT_VM(0);
        }
        __syncthreads();
        if (tid == 0) bumpf(hflag);
    }
}

// =================== fallback path (R2/R15 verbatim, proven) ===================
__global__ __launch_bounds__(256) void init_zero(float* __restrict__ ws) {
    int i = blockIdx.x * blockDim.x + threadIdx.x;
    if (i < BH) {
        ws[HBUF_OFF + i] = 0.f;
        ws[CBUF_OFF + i] = 0.f;
    }
}

__global__ __launch_bounds__(256) void attn_kernel(
    const float* __restrict__ x, const float* __restrict__ Wa,
    const float* __restrict__ Ua, const float* __restrict__ ba,
    const float* __restrict__ Va, float* __restrict__ ws, int t)
{
    const int d = threadIdx.x & 63;
    const int rr = (threadIdx.x >> 6) & 1;
    const int p = threadIdx.x >> 7;
    const int b = blockIdx.x * 2 + rr;

    const int rd = t & 1;
    const float* __restrict__ hrow = ws + HBUF_OFF + rd*BH + b*H;
    const float* __restrict__ crow = ws + CBUF_OFF + rd*BH + b*H;
    const float* __restrict__ xrow = x + ((size_t)b*S + t)*D;

    __shared__ float part[2][2][64];
    __shared__ float ta[2][64];
    __shared__ float pv[2][2][64];

    float a = 0.f;
    if (p == 0) {
        a = ba[d];
        #pragma unroll 8
        for (int k = 0; k < D; ++k) a += xrow[k] * Wa[k*D + d];
        #pragma unroll 8
        for (int k = 0; k < H; ++k) a += hrow[k] * Ua[k*D + d];
    } else {
        #pragma unroll 8
        for (int k = 0; k < H; ++k) a += crow[k] * Ua[(H + k)*D + d];
    }
    part[rr][p][d] = a;
    __syncthreads();
    if (p == 0) ta[rr][d] = tanhf(part[rr][0][d] + part[rr][1][d]);
    __syncthreads();
    float av = 0.f;
    {
        const int k0 = p * 32;
        #pragma unroll 8
        for (int k = k0; k < k0 + 32; ++k) av += ta[rr][k] * Va[k*D + d];
    }
    pv[rr][p][d] = av;
    __syncthreads();
    float v = pv[rr][0][d] + pv[rr][1][d];
    float m = v;
    #pragma unroll
    for (int o = 32; o > 0; o >>= 1) m = fmaxf(m, __shfl_xor(m, o));
    float e = expf(v - m);
    float ssum = e;
    #pragma unroll
    for (int o = 32; o > 0; o >>= 1) ssum += __shfl_xor(ssum, o);
    if (p == 0) {
        ws[XATT_OFF + b*D + d] = (e / ssum) * xrow[d];
    }
}

__global__ __launch_bounds__(256) void gates_kernel(
    const float* __restrict__ Wih, const float* __restrict__ Whh,
    const float* __restrict__ bih, const float* __restrict__ bhh,
    float* __restrict__ ws, int t)
{
    const int tm = threadIdx.x & 7;
    const int tn = threadIdx.x >> 3;
    const int u0 = blockIdx.x * 32;
    const int r0 = blockIdx.y * 32;
    const int u  = u0 + tn;

    __shared__ float h_lds[32][68];
    __shared__ float w_lds[4][32][68];

    const int rd = t & 1, wr = rd ^ 1;
    const float* __restrict__ hbuf_r = ws + HBUF_OFF + rd*BH;
    const float* __restrict__ cbuf_r = ws + CBUF_OFF + rd*BH;
    float* __restrict__ hbuf_w = ws + HBUF_OFF + wr*BH;
    float* __restrict__ cbuf_w = ws + CBUF_OFF + wr*BH;
    const float* __restrict__ xatt = ws + XATT_OFF;

    float acc[4][4];
    #pragma unroll
    for (int i = 0; i < 4; ++i)
        #pragma unroll
        for (int q = 0; q < 4; ++q) acc[i][q] = 0.f;

    for (int kb = 0; kb < 9; ++kb) {
        __syncthreads();
        {
            const float* src; int ldsrc, kofs;
            if (kb < 8) { src = Whh; ldsrc = H; kofs = kb*64; }
            else        { src = Wih; ldsrc = D; kofs = 0; }
            #pragma unroll
            for (int it = 0; it < 8; ++it) {
                int j = threadIdx.x + it*256;
                int f4c = j & 15, row = j >> 4;
                int uu = row & 31, q = row >> 5;
                float4 v = *reinterpret_cast<const float4*>(src + (size_t)(q*H + u0 + uu)*ldsrc + kofs + f4c*4);
                *reinterpret_cast<float4*>(&w_lds[q][uu][f4c*4]) = v;
            }
            const float* hsrc = (kb < 8) ? hbuf_r : xatt;
            int ldh  = (kb < 8) ? H : D;
            int kofs2 = (kb < 8) ? kb*64 : 0;
            #pragma unroll
            for (int it = 0; it < 2; ++it) {
                int j = threadIdx.x + it*256;
                int f4c = j & 15, rl = j >> 4;
                float4 v = *reinterpret_cast<const float4*>(hsrc + (size_t)(r0 + rl)*ldh + kofs2 + f4c*4);
                *reinterpret_cast<float4*>(&h_lds[rl][f4c*4]) = v;
            }
        }
        __syncthreads();
        #pragma unroll
        for (int k4 = 0; k4 < 16; ++k4) {
            float4 wv[4], hv[4];
            #pragma unroll
            for (int q = 0; q < 4; ++q)
                wv[q] = *reinterpret_cast<const float4*>(&w_lds[q][tn][k4*4]);
            #pragma unroll
            for (int i = 0; i < 4; ++i)
                hv[i] = *reinterpret_cast<const float4*>(&h_lds[tm + 8*i][k4*4]);
            #pragma unroll
            for (int i = 0; i < 4; ++i)
                #pragma unroll
                for (int q = 0; q < 4; ++q) {
                    acc[i][q] += hv[i].x * wv[q].x;
                    acc[i][q] += hv[i].y * wv[q].y;
                    acc[i][q] += hv[i].z * wv[q].z;
                    acc[i][q] += hv[i].w * wv[q].w;
                }
        }
    }

    float bsum[4];
    #pragma unroll
    for (int q = 0; q < 4; ++q) bsum[q] = bih[q*H + u] + bhh[q*H + u];

    #pragma unroll
    for (int i = 0; i < 4; ++i) {
        int b = r0 + tm + 8*i;
        float gi = acc[i][0] + bsum[0];
        float gf = acc[i][1] + bsum[1];
        float gg = acc[i][2] + bsum[2];
        float go = acc[i][3] + bsum[3];
        float c_old = cbuf_r[(size_t)b*H + u];
        float si = 1.f / (1.f + expf(-gi));
        float sf = 1.f / (1.f + expf(-gf));
        float so = 1.f / (1.f + expf(-go));
        float cn = sf * c_old + si * tanhf(gg);
        float hn = so * tanhf(cn);
        cbuf_w[(size_t)b*H + u] = cn;
        hbuf_w[(size_t)b*H + u] = hn;
    }
}

__global__ __launch_bounds__(256) void fc_kernel(
    const float* __restrict__ fcw, const float* __restrict__ fcb,
    const float* __restrict__ ws, float* __restrict__ out)
{
    const int b = blockIdx.x;
    __shared__ float hrow[H];
    const float* __restrict__ hp = ws + HBUF_OFF + (size_t)b*H;  // final h in slot 0
    for (int k = threadIdx.x; k < H; k += 256) hrow[k] = hp[k];
    __syncthreads();
    int j = threadIdx.x;
    if (j < 24) {
        float a = fcb[j];
        #pragma unroll 8
        for (int k = 0; k < H; ++k) a += hrow[k] * fcw[j*H + k];
        out[b*24 + j] = a;
    }
}

extern "C" void kernel_launch(void* const* d_in, const int* in_sizes, int n_in,
                              void* d_out, int out_size, void* d_ws, size_t ws_size,
                              hipStream_t stream) {
    const float* x   = (const float*)d_in[0];
    const float* Wa  = (const float*)d_in[1];
    const float* Ua  = (const float*)d_in[2];
    const float* ba  = (const float*)d_in[3];
    const float* Va  = (const float*)d_in[4];
    const float* Wih = (const float*)d_in[5];
    const float* Whh = (const float*)d_in[6];
    const float* bih = (const float*)d_in[7];
    const float* bhh = (const float*)d_in[8];
    const float* fcw = (const float*)d_in[9];
    const float* fcb = (const float*)d_in[10];
    float* out = (float*)d_out;
    float* ws  = (float*)d_ws;
    unsigned int* flags = (unsigned int*)(ws + FLAGS_OFF);
    const size_t NEED = (size_t)FLAGS_OFF * 4 + 4096;

    bool coop = (ws_size >= NEED);
    if (coop) {
        int maxBlk = 0;
        hipError_t oe = hipOccupancyMaxActiveBlocksPerMultiprocessor(
            &maxBlk, persist_kernel, 256, 0);
        coop = (oe == hipSuccess && maxBlk >= 1);
    }
    if (coop) {
        hipMemsetAsync(flags, 0, 4096, stream);
        void* args[] = {
            (void*)&x, (void*)&Wa, (void*)&Ua, (void*)&ba, (void*)&Va,
            (void*)&Wih, (void*)&Whh, (void*)&bih, (void*)&bhh,
            (void*)&ws, (void*)&flags
        };
        hipError_t rc = hipLaunchCooperativeKernel((void*)persist_kernel,
                            dim3(256), dim3(256), args, 0, stream);
        if (rc != hipSuccess) coop = false;
    }
    if (!coop) {   // proven fallback (R2 structure)
        hipLaunchKernelGGL(init_zero, dim3((BH + 255)/256), dim3(256), 0, stream, ws);
        for (int t = 0; t < S; ++t) {
            hipLaunchKernelGGL(attn_kernel, dim3(B/2), dim3(256), 0, stream,
                               x, Wa, Ua, ba, Va, ws, t);
            hipLaunchKernelGGL(gates_kernel, dim3(16, 16), dim3(256), 0, stream,
                               Wih, Whh, bih, bhh, ws, t);
        }
    }
    hipLaunchKernelGGL(fc_kernel, dim3(B), dim3(256), 0, stream, fcw, fcb, ws, out);
}

// Round 17
// 8655.615 us; speedup vs baseline: 1.4419x; 1.4419x over previous
//
#include <hip/hip_runtime.h>
#include <math.h>

#define B 512
#define S 256
#define D 64
#define H 512
#define BH (B*H)
#define KSTEPS 8

// ws floats: h 2 slots @0 | c 1 slot @2BH | xatt @3BH | flags(uint) @3BH+B*D
#define HBUF_OFF 0
#define CBUF_OFF (2*BH)
#define XATT_OFF (3*BH)
#define FLAGS_OFF (3*BH + B*D)
#define NFLAGS 1024

#define WAIT_VM0 asm volatile("s_waitcnt vmcnt(0)" ::: "memory")

__device__ __forceinline__ void ldg_sc(float4& r, const float* p) {
    asm volatile("global_load_dwordx4 %0, %1, off sc0 sc1" : "=v"(r) : "v"(p));
}
__device__ __forceinline__ void st_sc(float* p, float v) {
    asm volatile("global_store_dword %0, %1, off sc0 sc1" :: "v"(p), "v"(v));
}
__device__ __forceinline__ void waitf(unsigned int* f, unsigned int tgt) {
    if (threadIdx.x == 0) {
        unsigned int spin = 0;
        while (__hip_atomic_load(f, __ATOMIC_RELAXED, __HIP_MEMORY_SCOPE_AGENT) < tgt) {
            __builtin_amdgcn_s_sleep(2);
            if (++spin > (1u << 18)) break;   // finite bail: no hang
        }
    }
    __syncthreads();
}
__device__ __forceinline__ void bumpf(unsigned int* f) {
    __hip_atomic_fetch_add(f, 1u, __ATOMIC_RELAXED, __HIP_MEMORY_SCOPE_AGENT);
}

__global__ __launch_bounds__(256) void init_zero(float* __restrict__ ws) {
    int i = blockIdx.x * blockDim.x + threadIdx.x;
    if (i < BH) {
        ws[HBUF_OFF + i] = 0.f;   // h slot 0
        ws[CBUF_OFF + i] = 0.f;   // c
    }
    if (i < NFLAGS) ((unsigned int*)(ws + FLAGS_OFF))[i] = 0u;
}

// Fused 8-step kernel. 512 blocks: 0..255 attn duty (2 rows each),
// 256..511 gates duty (32 rows x 32 units, R2 tile). All co-resident
// (57.5KB LDS -> 2 blocks/CU x 256 CUs = 512). State h/c/xatt via sc0sc1;
// weights/inputs normal cached loads. Group-local monotonic flags.
__global__ __launch_bounds__(256, 2) void fused_kernel(
    const float* __restrict__ x, const float* __restrict__ Wa,
    const float* __restrict__ Ua, const float* __restrict__ ba,
    const float* __restrict__ Va,
    const float* __restrict__ Wih, const float* __restrict__ Whh,
    const float* __restrict__ bih, const float* __restrict__ bhh,
    float* __restrict__ ws, int base)
{
    const int bid = blockIdx.x;
    const int tid = threadIdx.x;
    float* h32 = ws + HBUF_OFF;
    float* c32 = ws + CBUF_OFF;
    float* xatt = ws + XATT_OFF;
    unsigned int* flags = (unsigned int*)(ws + FLAGS_OFF);

    __shared__ float h_lds[32][68];      // gates act tile   8.7 KB
    __shared__ float w_lds[4][32][68];   // gates W tile    34.8 KB
    __shared__ float c_t[32][36];        // gates c tile     4.6 KB
    __shared__ float h2[2][512];         // attn h rows      4.0 KB
    __shared__ float c2[2][512];         // attn c rows      4.0 KB
    __shared__ float part[2][2][64];
    __shared__ float ta[2][64];
    __shared__ float pv[2][2][64];

    if (bid < 256) {
        // ======================= attn duty =======================
        const int d = tid & 63;
        const int rr = (tid >> 6) & 1;
        const int p = tid >> 7;
        const int r_t = bid >> 4;                 // row-tile 0..15
        const int brow = bid * 2 + rr;
        unsigned int* hf = flags + r_t * 32;
        unsigned int* xf = flags + 512 + r_t * 32;

        for (int sub = 0; sub < KSTEPS; ++sub) {
            const int ts = base + sub;
            const int rd = ts & 1;
            waitf(hf, 16u * (unsigned int)ts);    // h(ts), c(ts) published

            {   // stage own 2 rows of h and c into LDS (sc)
                float4 hv, cv;
                const int row = bid * 2 + (tid >> 7);
                ldg_sc(hv, h32 + (size_t)rd * BH + (size_t)row * H + (tid & 127) * 4);
                ldg_sc(cv, c32 + (size_t)row * H + (tid & 127) * 4);
                WAIT_VM0;
                *(float4*)&h2[tid >> 7][(tid & 127) * 4] = hv;
                *(float4*)&c2[tid >> 7][(tid & 127) * 4] = cv;
            }
            __syncthreads();

            const float* __restrict__ xrow = x + ((size_t)brow * S + ts) * D;
            float a = 0.f;
            if (p == 0) {
                a = ba[d];
                #pragma unroll 8
                for (int k = 0; k < D; ++k) a += xrow[k] * Wa[k*D + d];
                #pragma unroll 8
                for (int k = 0; k < H; ++k) a += h2[rr][k] * Ua[k*D + d];
            } else {
                #pragma unroll 8
                for (int k = 0; k < H; ++k) a += c2[rr][k] * Ua[(size_t)(H + k)*D + d];
            }
            part[rr][p][d] = a;
            __syncthreads();
            if (p == 0) ta[rr][d] = tanhf(part[rr][0][d] + part[rr][1][d]);
            __syncthreads();
            float av = 0.f;
            {
                const int k0 = p * 32;
                #pragma unroll 8
                for (int k = k0; k < k0 + 32; ++k) av += ta[rr][k] * Va[k*D + d];
            }
            pv[rr][p][d] = av;
            __syncthreads();
            float v = pv[rr][0][d] + pv[rr][1][d];
            float m = v;
            #pragma unroll
            for (int o = 32; o > 0; o >>= 1) m = fmaxf(m, __shfl_xor(m, o));
            float e = expf(v - m);
            float ssum = e;
            #pragma unroll
            for (int o = 32; o > 0; o >>= 1) ssum += __shfl_xor(ssum, o);
            if (p == 0) {
                st_sc(xatt + (size_t)brow * D + d, (e / ssum) * xrow[d]);
            }
            WAIT_VM0;
            __syncthreads();
            if (tid == 0) bumpf(xf);
        }
    } else {
        // ======================= gates duty =======================
        const int g = bid - 256;
        const int u_t = g & 15, r_t = g >> 4;
        const int u0 = u_t * 32, r0 = r_t * 32;
        const int tm = tid & 7, tn = tid >> 3;
        const int u = u0 + tn;
        unsigned int* hf = flags + r_t * 32;
        unsigned int* xf = flags + 512 + r_t * 32;

        const float bs0 = bih[0*H + u] + bhh[0*H + u];
        const float bs1 = bih[1*H + u] + bhh[1*H + u];
        const float bs2 = bih[2*H + u] + bhh[2*H + u];
        const float bs3 = bih[3*H + u] + bhh[3*H + u];

        for (int sub = 0; sub < KSTEPS; ++sub) {
            const int ts = base + sub;
            const int rd = ts & 1, wrs = rd ^ 1;
            waitf(hf, 16u * (unsigned int)ts);    // h(ts), c(ts) published

            float acc[4][4];
            #pragma unroll
            for (int i = 0; i < 4; ++i)
                #pragma unroll
                for (int q = 0; q < 4; ++q) acc[i][q] = 0.f;

            for (int kb = 0; kb < 9; ++kb) {
                if (kb == 8) waitf(xf, 16u * (unsigned int)(ts + 1)); // xatt(ts)
                __syncthreads();
                {
                    // W stage (normal cached loads, R2 pattern)
                    const float* src; int ldsrc, kofs;
                    if (kb < 8) { src = Whh; ldsrc = H; kofs = kb*64; }
                    else        { src = Wih; ldsrc = D; kofs = 0; }
                    #pragma unroll
                    for (int it = 0; it < 8; ++it) {
                        int j = tid + it*256;
                        int f4c = j & 15, row = j >> 4;
                        int uu = row & 31, q = row >> 5;
                        float4 v = *(const float4*)(src + (size_t)(q*H + u0 + uu)*ldsrc + kofs + f4c*4);
                        *(float4*)&w_lds[q][uu][f4c*4] = v;
                    }
                    // activation stage (sc loads)
                    float4 a0, a1, ctv;
                    {
                        int j0 = tid, j1 = tid + 256;
                        int f0 = j0 & 15, rl0 = j0 >> 4;
                        int f1 = j1 & 15, rl1 = j1 >> 4;
                        if (kb < 8) {
                            const float* hb = h32 + (size_t)rd * BH;
                            ldg_sc(a0, hb + (size_t)(r0 + rl0)*H + kb*64 + f0*4);
                            ldg_sc(a1, hb + (size_t)(r0 + rl1)*H + kb*64 + f1*4);
                        } else {
                            ldg_sc(a0, xatt + (size_t)(r0 + rl0)*D + f0*4);
                            ldg_sc(a1, xatt + (size_t)(r0 + rl1)*D + f1*4);
                        }
                        if (kb == 0)
                            ldg_sc(ctv, c32 + (size_t)(r0 + (tid >> 3))*H + u0 + (tid & 7)*4);
                        WAIT_VM0;
                        *(float4*)&h_lds[rl0][f0*4] = a0;
                        *(float4*)&h_lds[rl1][f1*4] = a1;
                        if (kb == 0)
                            *(float4*)&c_t[tid >> 3][(tid & 7)*4] = ctv;
                    }
                }
                __syncthreads();
                #pragma unroll
                for (int k4 = 0; k4 < 16; ++k4) {
                    float4 wv[4], hv[4];
                    #pragma unroll
                    for (int q = 0; q < 4; ++q)
                        wv[q] = *(const float4*)&w_lds[q][tn][k4*4];
                    #pragma unroll
                    for (int i = 0; i < 4; ++i)
                        hv[i] = *(const float4*)&h_lds[tm + 8*i][k4*4];
                    #pragma unroll
                    for (int i = 0; i < 4; ++i)
                        #pragma unroll
                        for (int q = 0; q < 4; ++q) {
                            acc[i][q] = fmaf(hv[i].x, wv[q].x, acc[i][q]);
                            acc[i][q] = fmaf(hv[i].y, wv[q].y, acc[i][q]);
                            acc[i][q] = fmaf(hv[i].z, wv[q].z, acc[i][q]);
                            acc[i][q] = fmaf(hv[i].w, wv[q].w, acc[i][q]);
                        }
                }
            }

            // LSTM update + publish h(ts+1), c(ts+1) via sc
            float* __restrict__ hW = h32 + (size_t)wrs * BH;
            #pragma unroll
            for (int i = 0; i < 4; ++i) {
                const int b = r0 + tm + 8*i;
                float gi = acc[i][0] + bs0;
                float gf = acc[i][1] + bs1;
                float gg = acc[i][2] + bs2;
                float go = acc[i][3] + bs3;
                float c_old = c_t[tm + 8*i][tn];
                float si = 1.f / (1.f + expf(-gi));
                float sf = 1.f / (1.f + expf(-gf));
                float so = 1.f / (1.f + expf(-go));
                float cn = sf * c_old + si * tanhf(gg);
                float hn = so * tanhf(cn);
                st_sc(c32 + (size_t)b * H + u, cn);
                st_sc(hW + (size_t)b * H + u, hn);
            }
            WAIT_VM0;
            __syncthreads();
            if (tid == 0) bumpf(hf);
        }
    }
}

__global__ __launch_bounds__(256) void fc_kernel(
    const float* __restrict__ fcw, const float* __restrict__ fcb,
    const float* __restrict__ ws, float* __restrict__ out)
{
    const int b = blockIdx.x;
    __shared__ float hrow[H];
    const float* __restrict__ hp = ws + HBUF_OFF + (size_t)b*H;  // final h in slot 0
    for (int k = threadIdx.x; k < H; k += 256) hrow[k] = hp[k];
    __syncthreads();
    int j = threadIdx.x;
    if (j < 24) {
        float a = fcb[j];
        #pragma unroll 8
        for (int k = 0; k < H; ++k) a += hrow[k] * fcw[j*H + k];
        out[b*24 + j] = a;
    }
}

extern "C" void kernel_launch(void* const* d_in, const int* in_sizes, int n_in,
                              void* d_out, int out_size, void* d_ws, size_t ws_size,
                              hipStream_t stream) {
    const float* x   = (const float*)d_in[0];
    const float* Wa  = (const float*)d_in[1];
    const float* Ua  = (const float*)d_in[2];
    const float* ba  = (const float*)d_in[3];
    const float* Va  = (const float*)d_in[4];
    const float* Wih = (const float*)d_in[5];
    const float* Whh = (const float*)d_in[6];
    const float* bih = (const float*)d_in[7];
    const float* bhh = (const float*)d_in[8];
    const float* fcw = (const float*)d_in[9];
    const float* fcb = (const float*)d_in[10];
    float* out = (float*)d_out;
    float* ws  = (float*)d_ws;

    hipLaunchKernelGGL(init_zero, dim3((BH + 255)/256), dim3(256), 0, stream, ws);
    for (int base = 0; base < S; base += KSTEPS) {
        hipLaunchKernelGGL(fused_kernel, dim3(512), dim3(256), 0, stream,
                           x, Wa, Ua, ba, Va, Wih, Whh, bih, bhh, ws, base);
    }
    hipLaunchKernelGGL(fc_kernel, dim3(B), dim3(256), 0, stream, fcw, fcb, ws, out);
}